// Round 1
// baseline (230.027 us; speedup 1.0000x reference)
//
#include <hip/hip_runtime.h>

// diff_lpc2rc: per-row backward Levinson recursion on N=16 fp32 values.
// Rows: 64 * 32768 = 2,097,152. ~268 MB ideal HBM traffic -> ~43 us floor.
//
// R3 (kept): wave-private LDS staging kills the 4x cacheline-transaction
// amplification. 4 coalesced global loads -> LDS scatter -> per-lane row
// gather (stride-17-dword rows: worst aliasing 2-way = free) -> recursion in
// registers -> LDS -> coalesced stores. No __syncthreads needed.
//
// R4: (a) deferred-scale recursion. All active positions share the same
// accumulated 1/(1-k^2) product, so keep A[] unscaled and one scalar inv_s:
//   k        = A[len] * inv_s        (true k; also the final output at [len])
//   inv_s   *= rcp(1 - k*k)
//   A[m]    -= k * A[j]  (single fma per element, was fma+mul)
//   out[0]   = A[0] * inv_s at the end
// Cuts recursion VALU ~270 -> ~181 instr/lane (-33%); VALU was ~37 us/CU vs
// ~43 us HBM floor, i.e. co-dominant with memory.
// (b) nontemporal stores: output is never re-read; don't let it evict the
// 134 MB input from the 256 MB L3 across graph replays.

constexpr int N = 16;
constexpr int RS = 17;             // LDS row stride in dwords (68 B) - bank decorrelation
constexpr int WAVES_PER_WG = 4;    // 256 threads

typedef float f32x4 __attribute__((ext_vector_type(4)));

__global__ __launch_bounds__(256) void lpc2rc_kernel(const float* __restrict__ x,
                                                     float* __restrict__ out,
                                                     int nrows) {
    __shared__ float lds[WAVES_PER_WG * 64 * RS];   // 17408 B

    const int tid  = threadIdx.x;
    const int wave = tid >> 6;
    const int lane = tid & 63;
    float* __restrict__ wlds = lds + wave * 64 * RS;

    const long long wave_row0 = ((long long)blockIdx.x * WAVES_PER_WG + wave) * 64;

    float a[N];

    if (wave_row0 + 64 <= (long long)nrows) {
        // ---- fast path: full 64-row tile, fully coalesced ----
        const f32x4* __restrict__ in4 = (const f32x4*)x;
        f32x4* __restrict__ out4 = (f32x4*)out;
        const long long base4 = wave_row0 * 4;   // float4 index of tile start

        // 4 coalesced loads: float4 #(base4 + c*64 + lane)
        f32x4 ld[4];
#pragma unroll
        for (int c = 0; c < 4; ++c)
            ld[c] = in4[base4 + (long long)(c * 64 + lane)];

        // scatter to LDS: float4 f = c*64+lane -> row 16c + (lane>>2), elems 4*(lane&3)..+3
#pragma unroll
        for (int c = 0; c < 4; ++c) {
            float* p = wlds + (16 * c + (lane >> 2)) * RS + 4 * (lane & 3);
            p[0] = ld[c].x; p[1] = ld[c].y; p[2] = ld[c].z; p[3] = ld[c].w;
        }

        // gather own row (lane l reads addr l*17+e: 2-way bank alias only)
        {
            const float* p = wlds + lane * RS;
#pragma unroll
            for (int e = 0; e < N; ++e) a[e] = p[e];
        }

        // ---- deferred-scale backward Levinson recursion, in registers ----
        float inv_s = 1.0f;
#pragma unroll
        for (int i = 1; i < N; ++i) {
            const int len = N - i;
            const float k = a[len] * inv_s;     // true reflection coeff = final out[len]
            a[len] = k;
            const float r = __builtin_amdgcn_rcpf(1.0f - k * k);
            inv_s *= r;
#pragma unroll
            for (int m = 0; m < len / 2; ++m) {
                const int j = len - 1 - m;
                const float am = a[m];
                const float aj = a[j];
                a[m] = __builtin_fmaf(-k, aj, am);
                a[j] = __builtin_fmaf(-k, am, aj);
            }
            if (len & 1) {
                const int mid = len / 2;
                const float t = a[mid];
                a[mid] = __builtin_fmaf(-k, t, t);
            }
        }
        a[0] *= inv_s;

        // write row back to LDS
        {
            float* p = wlds + lane * RS;
#pragma unroll
            for (int e = 0; e < N; ++e) p[e] = a[e];
        }

        // coalesced nontemporal stores (reverse of the load distribution)
#pragma unroll
        for (int c = 0; c < 4; ++c) {
            const float* p = wlds + (16 * c + (lane >> 2)) * RS + 4 * (lane & 3);
            f32x4 v;
            v.x = p[0]; v.y = p[1]; v.z = p[2]; v.w = p[3];
            __builtin_nontemporal_store(v, &out4[base4 + (long long)(c * 64 + lane)]);
        }
    } else {
        // ---- tail path: per-lane guarded (rare/absent for this shape) ----
        const long long r = wave_row0 + lane;
        if (r >= (long long)nrows) return;
        const f32x4* __restrict__ in4 = (const f32x4*)x;
        f32x4* __restrict__ out4 = (f32x4*)out;
        f32x4 v0 = in4[r * 4 + 0], v1 = in4[r * 4 + 1],
              v2 = in4[r * 4 + 2], v3 = in4[r * 4 + 3];
        a[0]=v0.x; a[1]=v0.y; a[2]=v0.z; a[3]=v0.w;
        a[4]=v1.x; a[5]=v1.y; a[6]=v1.z; a[7]=v1.w;
        a[8]=v2.x; a[9]=v2.y; a[10]=v2.z; a[11]=v2.w;
        a[12]=v3.x; a[13]=v3.y; a[14]=v3.z; a[15]=v3.w;

        float inv_s = 1.0f;
#pragma unroll
        for (int i = 1; i < N; ++i) {
            const int len = N - i;
            const float k = a[len] * inv_s;
            a[len] = k;
            const float rr = __builtin_amdgcn_rcpf(1.0f - k * k);
            inv_s *= rr;
#pragma unroll
            for (int m = 0; m < len / 2; ++m) {
                const int j = len - 1 - m;
                const float am = a[m], aj = a[j];
                a[m] = __builtin_fmaf(-k, aj, am);
                a[j] = __builtin_fmaf(-k, am, aj);
            }
            if (len & 1) {
                const int mid = len / 2;
                const float t = a[mid];
                a[mid] = __builtin_fmaf(-k, t, t);
            }
        }
        a[0] *= inv_s;

        v0.x=a[0]; v0.y=a[1]; v0.z=a[2]; v0.w=a[3];
        v1.x=a[4]; v1.y=a[5]; v1.z=a[6]; v1.w=a[7];
        v2.x=a[8]; v2.y=a[9]; v2.z=a[10]; v2.w=a[11];
        v3.x=a[12]; v3.y=a[13]; v3.z=a[14]; v3.w=a[15];
        __builtin_nontemporal_store(v0, &out4[r * 4 + 0]);
        __builtin_nontemporal_store(v1, &out4[r * 4 + 1]);
        __builtin_nontemporal_store(v2, &out4[r * 4 + 2]);
        __builtin_nontemporal_store(v3, &out4[r * 4 + 3]);
    }
}

extern "C" void kernel_launch(void* const* d_in, const int* in_sizes, int n_in,
                              void* d_out, int out_size, void* d_ws, size_t ws_size,
                              hipStream_t stream) {
    const float* x = (const float*)d_in[0];
    float* out = (float*)d_out;
    const int nrows = in_sizes[0] / N;                 // 2,097,152
    const int rows_per_wg = 64 * WAVES_PER_WG;         // 256
    const int grid = (nrows + rows_per_wg - 1) / rows_per_wg;   // 8192
    lpc2rc_kernel<<<grid, 256, 0, stream>>>(x, out, nrows);
}

// Round 4
// 227.567 us; speedup vs baseline: 1.0108x; 1.0108x over previous
//
#include <hip/hip_runtime.h>

// diff_lpc2rc: per-row backward Levinson recursion on N=16 fp32 values.
// Rows: 64 * 32768 = 2,097,152. ~268 MB HBM traffic; copy-ceiling ~43 us.
//
// R5c: fixes R5b's correctness failure (absmax 14.79). Root cause: DPP
// (convergent cross-lane op) was evaluated INSIDE a per-lane-divergent
// ternary -> compiled as a divergent branch -> half the wave inactive ->
// bound_ctrl made inactive source lanes read 0. Fix: every DPP executes
// unconditionally (straight-line, full exec); the per-lane choice is a
// plain value select (v_cndmask) on already-computed values.
//
// Structure (from R5): LDS fully eliminated. Lane l=4g+q's coalesced
// float4 load ld[c] holds quarter q of row 16c+g; a 4x4 transpose of
// float4s WITHIN each 4-lane quad (2-stage xor butterfly: xor2 then xor1,
// via DPP quad_perm on the VALU pipe) gives lane 4g+q the full row 16q+g
// in registers. The map is an involution, so the store side reuses the
// same butterfly. Replaces 64 LDS dword-ops + 4 dependent ~120cy LDS
// latency hops per lane (R3/R4's bottleneck; R4 proved VALU-cutting alone
// moved nothing, kernel was stuck at 79.7us vs ~43us copy floor).
// R4 deferred-scale recursion kept (verified passing in R1).

constexpr int N = 16;
constexpr int WAVES_PER_WG = 4;    // 256 threads

typedef float f32x4 __attribute__((ext_vector_type(4)));

__device__ __forceinline__ float dpp_xor2(float x) {
    // quad_perm [2,3,0,1] = 0x4E : lane q reads lane q^2 within its quad
    const int xi = __float_as_int(x);
    return __int_as_float(__builtin_amdgcn_update_dpp(xi, xi, 0x4E, 0xF, 0xF, true));
}
__device__ __forceinline__ float dpp_xor1(float x) {
    // quad_perm [1,0,3,2] = 0xB1 : lane q reads lane q^1 within its quad
    const int xi = __float_as_int(x);
    return __int_as_float(__builtin_amdgcn_update_dpp(xi, xi, 0xB1, 0xF, 0xF, true));
}

__global__ __launch_bounds__(256, 8) void lpc2rc_kernel(const float* __restrict__ x,
                                                        float* __restrict__ out,
                                                        int nrows) {
    const int tid  = threadIdx.x;
    const int lane = tid & 63;

    const long long wave_row0 = ((long long)blockIdx.x * WAVES_PER_WG + (tid >> 6)) * 64;

    float a[N];

    if (wave_row0 + 64 <= (long long)nrows) {
        // ---- fast path: full 64-row tile, fully coalesced, no LDS ----
        const f32x4* __restrict__ in4 = (const f32x4*)x;
        f32x4* __restrict__ out4 = (f32x4*)out;
        const long long base4 = wave_row0 * 4;   // float4 index of tile start

        // 4 coalesced loads. Lane l = 4g+q gets ld[c] = quarter q of row 16c+g.
        f32x4 ld[4];
#pragma unroll
        for (int c = 0; c < 4; ++c)
            ld[c] = in4[base4 + (long long)(c * 64 + lane)];

        const bool hi = (lane >> 1) & 1;   // bit1 of q
        const bool lo = lane & 1;          // bit0 of q

        // ---- quad transpose (butterfly): lane 4g+q ends with row 16q+g ----
        // All DPP ops unconditional (full exec); selection via cndmask only.
        float W[4][4];
#pragma unroll
        for (int t = 0; t < 4; ++t) {
            const float x0 = dpp_xor2(ld[0][t]);
            const float x1 = dpp_xor2(ld[1][t]);
            const float x2 = dpp_xor2(ld[2][t]);
            const float x3 = dpp_xor2(ld[3][t]);
            W[0][t] = hi ? x2 : ld[0][t];
            W[1][t] = hi ? x3 : ld[1][t];
            W[2][t] = hi ? ld[2][t] : x0;
            W[3][t] = hi ? ld[3][t] : x1;
        }
#pragma unroll
        for (int t = 0; t < 4; ++t) {
            const float y0 = dpp_xor1(W[0][t]);
            const float y1 = dpp_xor1(W[1][t]);
            const float y2 = dpp_xor1(W[2][t]);
            const float y3 = dpp_xor1(W[3][t]);
            a[0  + t] = lo ? y1 : W[0][t];
            a[4  + t] = lo ? W[1][t] : y0;
            a[8  + t] = lo ? y3 : W[2][t];
            a[12 + t] = lo ? W[3][t] : y2;
        }

        // ---- deferred-scale backward Levinson recursion, in registers ----
        float inv_s = 1.0f;
#pragma unroll
        for (int i = 1; i < N; ++i) {
            const int len = N - i;
            const float k = a[len] * inv_s;     // true reflection coeff = final out[len]
            a[len] = k;
            const float r = __builtin_amdgcn_rcpf(1.0f - k * k);
            inv_s *= r;
#pragma unroll
            for (int m = 0; m < len / 2; ++m) {
                const int j = len - 1 - m;
                const float am = a[m];
                const float aj = a[j];
                a[m] = __builtin_fmaf(-k, aj, am);
                a[j] = __builtin_fmaf(-k, am, aj);
            }
            if (len & 1) {
                const int mid = len / 2;
                const float t = a[mid];
                a[mid] = __builtin_fmaf(-k, t, t);
            }
        }
        a[0] *= inv_s;

        // ---- inverse quad transpose (same butterfly - involution) ----
#pragma unroll
        for (int t = 0; t < 4; ++t) {
            const float x0 = dpp_xor2(a[0  + t]);
            const float x1 = dpp_xor2(a[4  + t]);
            const float x2 = dpp_xor2(a[8  + t]);
            const float x3 = dpp_xor2(a[12 + t]);
            W[0][t] = hi ? x2 : a[0  + t];
            W[1][t] = hi ? x3 : a[4  + t];
            W[2][t] = hi ? a[8  + t] : x0;
            W[3][t] = hi ? a[12 + t] : x1;
        }
        f32x4 st[4];
#pragma unroll
        for (int t = 0; t < 4; ++t) {
            const float y0 = dpp_xor1(W[0][t]);
            const float y1 = dpp_xor1(W[1][t]);
            const float y2 = dpp_xor1(W[2][t]);
            const float y3 = dpp_xor1(W[3][t]);
            st[0][t] = lo ? y1 : W[0][t];
            st[1][t] = lo ? W[1][t] : y0;
            st[2][t] = lo ? y3 : W[2][t];
            st[3][t] = lo ? W[3][t] : y2;
        }

        // coalesced stores (exact mirror of the load distribution)
#pragma unroll
        for (int c = 0; c < 4; ++c)
            out4[base4 + (long long)(c * 64 + lane)] = st[c];
    } else {
        // ---- tail path: per-lane guarded (absent for this shape) ----
        const long long r = wave_row0 + lane;
        if (r >= (long long)nrows) return;
        const f32x4* __restrict__ in4 = (const f32x4*)x;
        f32x4* __restrict__ out4 = (f32x4*)out;
        f32x4 v0 = in4[r * 4 + 0], v1 = in4[r * 4 + 1],
              v2 = in4[r * 4 + 2], v3 = in4[r * 4 + 3];
        a[0]=v0.x; a[1]=v0.y; a[2]=v0.z; a[3]=v0.w;
        a[4]=v1.x; a[5]=v1.y; a[6]=v1.z; a[7]=v1.w;
        a[8]=v2.x; a[9]=v2.y; a[10]=v2.z; a[11]=v2.w;
        a[12]=v3.x; a[13]=v3.y; a[14]=v3.z; a[15]=v3.w;

        float inv_s = 1.0f;
#pragma unroll
        for (int i = 1; i < N; ++i) {
            const int len = N - i;
            const float k = a[len] * inv_s;
            a[len] = k;
            const float rr = __builtin_amdgcn_rcpf(1.0f - k * k);
            inv_s *= rr;
#pragma unroll
            for (int m = 0; m < len / 2; ++m) {
                const int j = len - 1 - m;
                const float am = a[m], aj = a[j];
                a[m] = __builtin_fmaf(-k, aj, am);
                a[j] = __builtin_fmaf(-k, am, aj);
            }
            if (len & 1) {
                const int mid = len / 2;
                const float t = a[mid];
                a[mid] = __builtin_fmaf(-k, t, t);
            }
        }
        a[0] *= inv_s;

        v0.x=a[0]; v0.y=a[1]; v0.z=a[2]; v0.w=a[3];
        v1.x=a[4]; v1.y=a[5]; v1.z=a[6]; v1.w=a[7];
        v2.x=a[8]; v2.y=a[9]; v2.z=a[10]; v2.w=a[11];
        v3.x=a[12]; v3.y=a[13]; v3.z=a[14]; v3.w=a[15];
        out4[r * 4 + 0] = v0; out4[r * 4 + 1] = v1;
        out4[r * 4 + 2] = v2; out4[r * 4 + 3] = v3;
    }
}

extern "C" void kernel_launch(void* const* d_in, const int* in_sizes, int n_in,
                              void* d_out, int out_size, void* d_ws, size_t ws_size,
                              hipStream_t stream) {
    const float* x = (const float*)d_in[0];
    float* out = (float*)d_out;
    const int nrows = in_sizes[0] / N;                 // 2,097,152
    const int rows_per_wg = 64 * WAVES_PER_WG;         // 256
    const int grid = (nrows + rows_per_wg - 1) / rows_per_wg;   // 8192
    lpc2rc_kernel<<<grid, 256, 0, stream>>>(x, out, nrows);
}